// Round 1
// baseline (4075.333 us; speedup 1.0000x reference)
//
#include <hip/hip_runtime.h>

typedef _Float16 f16;
typedef _Float16 h2 __attribute__((ext_vector_type(2)));
typedef _Float16 h8 __attribute__((ext_vector_type(8)));

#define INV_SQRT_C 0.08838834764831845f

// ---------------- conv1: 3->32, stride 1, 256x256, ReLU, fp16 out ----------------
__global__ __launch_bounds__(256) void conv1_k(const float* __restrict__ img,
    const float* __restrict__ w1, const float* __restrict__ b1, f16* __restrict__ out)
{
  const int h = blockIdx.x, b = blockIdx.y;
  const int w = threadIdx.x;
  __shared__ float sIn[3][3][258];
  const float* imgb = img + (long)b * 3 * 65536;
  for (int idx = threadIdx.x; idx < 3 * 3 * 258; idx += 256) {
    int col = idx % 258; int t2 = idx / 258; int r = t2 % 3; int c = t2 / 3;
    int ih = h - 1 + r, iw = col - 1;
    float v = 0.f;
    if (ih >= 0 && ih < 256 && iw >= 0 && iw < 256) v = imgb[c * 65536 + ih * 256 + iw];
    sIn[c][r][col] = v;
  }
  __syncthreads();
  float acc[32];
  #pragma unroll
  for (int u = 0; u < 32; u++) acc[u] = b1[u];
  for (int c = 0; c < 3; c++)
    #pragma unroll
    for (int kh = 0; kh < 3; kh++)
      #pragma unroll
      for (int kw = 0; kw < 3; kw++) {
        float v = sIn[c][kh][w + kw];
        #pragma unroll
        for (int u = 0; u < 32; u++) acc[u] = fmaf(v, w1[(u * 3 + c) * 9 + kh * 3 + kw], acc[u]);
      }
  f16* ob = out + ((long)b * 32 * 65536) + h * 256 + w;
  #pragma unroll
  for (int u = 0; u < 32; u++) {
    float r = acc[u] > 0.f ? acc[u] : 0.f;
    ob[(long)u * 65536] = (f16)r;
  }
}

// ---------------- conv2: 32->64, stride 2, out 128x128, ReLU, fp16 out ----------------
__global__ __launch_bounds__(256) void conv2_k(const f16* __restrict__ in,
    const float* __restrict__ w2, const float* __restrict__ b2, f16* __restrict__ out)
{
  const int ohb = blockIdx.x * 2, b = blockIdx.y, oc0 = blockIdx.z * 32;
  const int ow = threadIdx.x & 127, q = threadIdx.x >> 7;
  __shared__ float sIn[8][5][258];
  float acc[32];
  #pragma unroll
  for (int u = 0; u < 32; u++) acc[u] = b2[oc0 + u];
  const int ihb = 2 * ohb - 1;
  for (int cc = 0; cc < 4; cc++) {
    __syncthreads();
    for (int idx = threadIdx.x; idx < 8 * 5 * 258; idx += 256) {
      int col = idx % 258; int t2 = idx / 258; int r = t2 % 5; int c = t2 / 5;
      int ih = ihb + r, iw = col - 1;
      float v = 0.f;
      if (ih >= 0 && ih < 256 && iw >= 0 && iw < 256)
        v = (float)in[((long)(b * 32 + cc * 8 + c) * 256 + ih) * 256 + iw];
      sIn[c][r][col] = v;
    }
    __syncthreads();
    for (int c = 0; c < 8; c++)
      #pragma unroll
      for (int kh = 0; kh < 3; kh++) {
        const int r = 2 * q + kh;
        #pragma unroll
        for (int kw = 0; kw < 3; kw++) {
          float v = sIn[c][r][2 * ow + kw];
          const float* wp = w2 + ((long)oc0 * 32 + cc * 8 + c) * 9 + kh * 3 + kw;
          #pragma unroll
          for (int u = 0; u < 32; u++) acc[u] = fmaf(v, wp[(long)u * 288], acc[u]);
        }
      }
  }
  const int oh = ohb + q;
  f16* ob = out + ((long)(b * 64 + oc0) * 128 + oh) * 128 + ow;
  #pragma unroll
  for (int u = 0; u < 32; u++) {
    float r = acc[u] > 0.f ? acc[u] : 0.f;
    ob[(long)u * 16384] = (f16)r;
  }
}

// ------- conv3: 64->128, stride 2, out 64x64, ReLU; fp32 NCHW to d_out + fp16 NHWC to ws -------
__global__ __launch_bounds__(256) void conv3_k(const f16* __restrict__ in,
    const float* __restrict__ w3, const float* __restrict__ b3,
    float* __restrict__ zout, f16* __restrict__ nhwc)
{
  const int ohb = blockIdx.x * 4, b = blockIdx.y, oc0 = blockIdx.z * 32;
  const int ow = threadIdx.x & 63, q = threadIdx.x >> 6;
  __shared__ float sIn[8][9][130];
  float acc[32];
  #pragma unroll
  for (int u = 0; u < 32; u++) acc[u] = b3[oc0 + u];
  const int ihb = 2 * ohb - 1;
  for (int cc = 0; cc < 8; cc++) {
    __syncthreads();
    for (int idx = threadIdx.x; idx < 8 * 9 * 130; idx += 256) {
      int col = idx % 130; int t2 = idx / 130; int r = t2 % 9; int c = t2 / 9;
      int ih = ihb + r, iw = col - 1;
      float v = 0.f;
      if (ih >= 0 && ih < 128 && iw >= 0 && iw < 128)
        v = (float)in[((long)(b * 64 + cc * 8 + c) * 128 + ih) * 128 + iw];
      sIn[c][r][col] = v;
    }
    __syncthreads();
    for (int c = 0; c < 8; c++)
      #pragma unroll
      for (int kh = 0; kh < 3; kh++) {
        const int r = 2 * q + kh;
        #pragma unroll
        for (int kw = 0; kw < 3; kw++) {
          float v = sIn[c][r][2 * ow + kw];
          const float* wp = w3 + ((long)oc0 * 64 + cc * 8 + c) * 9 + kh * 3 + kw;
          #pragma unroll
          for (int u = 0; u < 32; u++) acc[u] = fmaf(v, wp[(long)u * 576], acc[u]);
        }
      }
  }
  const int oh = ohb + q;
  float* zb = zout + ((long)(b * 128 + oc0) * 64 + oh) * 64 + ow;
  #pragma unroll
  for (int u = 0; u < 32; u++) {
    float rv = acc[u] > 0.f ? acc[u] : 0.f;
    zb[(long)u * 4096] = rv;
    acc[u] = rv;
  }
  h8* np8 = (h8*)(nhwc + ((long)(b * 64 + oh) * 64 + ow) * 128 + oc0);
  #pragma unroll
  for (int v8 = 0; v8 < 4; v8++) {
    h8 pk;
    #pragma unroll
    for (int k = 0; k < 8; k++) pk[k] = (f16)acc[v8 * 8 + k];
    np8[v8] = pk;
  }
}

// ---------------- local correlation: K=13, C=128, from fp16 NHWC z ----------------
__global__ __launch_bounds__(256) void corr_k(const f16* __restrict__ zt, const f16* __restrict__ zt1,
    float* __restrict__ corr)
{
  const int h = blockIdx.x, b = blockIdx.y;
  __shared__ h8 sT[64][17];  // row stride 272B -> 68 dwords % 32 = 4: conflict-optimal b128
  __shared__ h8 sU[64][17];
  const h8* tp = (const h8*)(zt + ((long)(b * 64 + h) * 64) * 128);
  for (int idx = threadIdx.x; idx < 1024; idx += 256)
    sT[idx >> 4][idx & 15] = tp[idx];
  const int w = threadIdx.x & 63, g = threadIdx.x >> 6;
  float* cb = corr + (long)b * 169 * 4096 + h * 64 + w;
  int wc[4]; bool ok[4];
  #pragma unroll
  for (int j = 0; j < 4; j++) {
    int kj = g * 4 + j;
    wc[j] = w + kj - 6;
    ok[j] = (kj < 13) && (wc[j] >= 0) && (wc[j] < 64);
  }
  for (int ki = 0; ki < 13; ki++) {
    int row = h + ki - 6;  // block-uniform
    if (row < 0 || row > 63) {
      #pragma unroll
      for (int j = 0; j < 4; j++) {
        int kj = g * 4 + j;
        if (kj < 13) cb[(long)(ki * 13 + kj) * 4096] = 0.f;
      }
      continue;
    }
    __syncthreads();
    const h8* up = (const h8*)(zt1 + ((long)(b * 64 + row) * 64) * 128);
    for (int idx = threadIdx.x; idx < 1024; idx += 256)
      sU[idx >> 4][idx & 15] = up[idx];
    __syncthreads();
    float a[4] = {0.f, 0.f, 0.f, 0.f};
    for (int c8 = 0; c8 < 16; c8++) {
      h8 tv = sT[w][c8];
      #pragma unroll
      for (int j = 0; j < 4; j++) {
        if (!ok[j]) continue;
        h8 uv = sU[wc[j]][c8];
#if __has_builtin(__builtin_amdgcn_fdot2)
        a[j] = __builtin_amdgcn_fdot2(__builtin_shufflevector(tv, tv, 0, 1),
                                      __builtin_shufflevector(uv, uv, 0, 1), a[j], false);
        a[j] = __builtin_amdgcn_fdot2(__builtin_shufflevector(tv, tv, 2, 3),
                                      __builtin_shufflevector(uv, uv, 2, 3), a[j], false);
        a[j] = __builtin_amdgcn_fdot2(__builtin_shufflevector(tv, tv, 4, 5),
                                      __builtin_shufflevector(uv, uv, 4, 5), a[j], false);
        a[j] = __builtin_amdgcn_fdot2(__builtin_shufflevector(tv, tv, 6, 7),
                                      __builtin_shufflevector(uv, uv, 6, 7), a[j], false);
#else
        #pragma unroll
        for (int k = 0; k < 8; k++) a[j] += (float)tv[k] * (float)uv[k];
#endif
      }
    }
    #pragma unroll
    for (int j = 0; j < 4; j++) {
      int kj = g * 4 + j;
      if (kj < 13) cb[(long)(ki * 13 + kj) * 4096] = a[j] * INV_SQRT_C;
    }
  }
}

// ---------------- h_t: mean over 64x64 per (b, offset) ----------------
__global__ __launch_bounds__(256) void ht_k(const float* __restrict__ corr, float* __restrict__ ht)
{
  const float4* p = (const float4*)(corr + (long)blockIdx.x * 4096);
  float s = 0.f;
  for (int i = threadIdx.x; i < 1024; i += 256) {
    float4 v = p[i];
    s += v.x + v.y + v.z + v.w;
  }
  #pragma unroll
  for (int off = 32; off > 0; off >>= 1) s += __shfl_down(s, off, 64);
  __shared__ float ps[4];
  if ((threadIdx.x & 63) == 0) ps[threadIdx.x >> 6] = s;
  __syncthreads();
  if (threadIdx.x == 0) ht[blockIdx.x] = (ps[0] + ps[1] + ps[2] + ps[3]) * (1.f / 4096.f);
}

// ---------------- pred: h_t @ w_head.T + b_head ----------------
__global__ void pred_k(const float* __restrict__ ht, const float* __restrict__ wh,
                       const float* __restrict__ bh, float* __restrict__ pred)
{
  int t = threadIdx.x;
  int b = t >> 1, j = t & 1;
  float s = bh[j];
  for (int o = 0; o < 169; o++) s = fmaf(ht[b * 169 + o], wh[j * 169 + o], s);
  pred[b * 2 + j] = s;
}

extern "C" void kernel_launch(void* const* d_in, const int* in_sizes, int n_in,
                              void* d_out, int out_size, void* d_ws, size_t ws_size,
                              hipStream_t stream)
{
  (void)in_sizes; (void)n_in; (void)out_size; (void)ws_size;
  const float* img_t  = (const float*)d_in[0];
  const float* img_t1 = (const float*)d_in[1];
  const float* w1 = (const float*)d_in[2];
  const float* b1 = (const float*)d_in[3];
  const float* w2 = (const float*)d_in[4];
  const float* b2 = (const float*)d_in[5];
  const float* w3 = (const float*)d_in[6];
  const float* b3 = (const float*)d_in[7];
  const float* wh = (const float*)d_in[8];
  const float* bh = (const float*)d_in[9];
  float* out = (float*)d_out;

  // workspace layout (fp16 intermediates, 256 MiB total)
  char* ws = (char*)d_ws;
  f16* bufA = (f16*)ws;                       // conv1 out: 32*32*256*256*2 = 128 MiB
  f16* bufB = (f16*)(ws + 134217728L);        // conv2 out: 32*64*128*128*2 =  64 MiB
  f16* nhT  = (f16*)(ws + 201326592L);        // z_t  NHWC: 32*64*64*128*2 =  32 MiB
  f16* nhT1 = (f16*)(ws + 234881024L);        // z_t1 NHWC:                   32 MiB

  const long OUT_ZT   = 64;
  const long OUT_ZT1  = OUT_ZT + 16777216L;
  const long OUT_CORR = OUT_ZT1 + 16777216L;
  const long OUT_HT   = OUT_CORR + 22151168L;

  for (int img = 0; img < 2; img++) {
    const float* src = img ? img_t1 : img_t;
    float* zdst = out + (img ? OUT_ZT1 : OUT_ZT);
    f16* nh = img ? nhT1 : nhT;
    conv1_k<<<dim3(256, 32), 256, 0, stream>>>(src, w1, b1, bufA);
    conv2_k<<<dim3(64, 32, 2), 256, 0, stream>>>(bufA, w2, b2, bufB);
    conv3_k<<<dim3(16, 32, 4), 256, 0, stream>>>(bufB, w3, b3, zdst, nh);
  }
  corr_k<<<dim3(64, 32), 256, 0, stream>>>(nhT, nhT1, out + OUT_CORR);
  ht_k<<<5408, 256, 0, stream>>>(out + OUT_CORR, out + OUT_HT);
  pred_k<<<1, 64, 0, stream>>>(out + OUT_HT, wh, bh, out);
}

// Round 2
// 976.801 us; speedup vs baseline: 4.1721x; 4.1721x over previous
//
#include <hip/hip_runtime.h>

typedef _Float16 f16;
typedef _Float16 h4 __attribute__((ext_vector_type(4)));
typedef _Float16 v8h __attribute__((ext_vector_type(8)));
typedef _Float16 h8 __attribute__((ext_vector_type(8)));
typedef float v4f __attribute__((ext_vector_type(4)));

#define INV_SQRT_C 0.08838834764831845f

// ---------------- conv1: 3->32, stride 1, 256x256, ReLU, NHWC fp16 out ----------------
__global__ __launch_bounds__(256) void conv1_k(const float* __restrict__ img,
    const float* __restrict__ w1, const float* __restrict__ b1, f16* __restrict__ out)
{
  const int h = blockIdx.x, b = blockIdx.y;
  const int w = threadIdx.x;
  __shared__ float sIn[3][3][258];
  const float* imgb = img + (long)b * 3 * 65536;
  for (int idx = threadIdx.x; idx < 3 * 3 * 258; idx += 256) {
    int col = idx % 258; int t2 = idx / 258; int r = t2 % 3; int c = t2 / 3;
    int ih = h - 1 + r, iw = col - 1;
    float v = 0.f;
    if (ih >= 0 && ih < 256 && iw >= 0 && iw < 256) v = imgb[c * 65536 + ih * 256 + iw];
    sIn[c][r][col] = v;
  }
  __syncthreads();
  float acc[32];
  #pragma unroll
  for (int u = 0; u < 32; u++) acc[u] = b1[u];
  for (int c = 0; c < 3; c++)
    #pragma unroll
    for (int kh = 0; kh < 3; kh++)
      #pragma unroll
      for (int kw = 0; kw < 3; kw++) {
        float v = sIn[c][kh][w + kw];
        #pragma unroll
        for (int u = 0; u < 32; u++) acc[u] = fmaf(v, w1[(u * 3 + c) * 9 + kh * 3 + kw], acc[u]);
      }
  // NHWC store: 32 contiguous f16 per thread
  h8* o8 = (h8*)(out + (((long)(b * 256 + h) * 256) + w) * 32);
  #pragma unroll
  for (int v8 = 0; v8 < 4; v8++) {
    h8 pk;
    #pragma unroll
    for (int k = 0; k < 8; k++) {
      float r = acc[v8 * 8 + k];
      pk[k] = (f16)(r > 0.f ? r : 0.f);
    }
    o8[v8] = pk;
  }
}

// ---------------- weight transforms: OIHW fp32 -> [khkw][oc][ic] fp16 ----------------
__global__ void wt2_k(const float* __restrict__ w2, f16* __restrict__ wT)
{
  int idx = blockIdx.x * 256 + threadIdx.x;          // 18432
  int ic = idx & 31, oc = (idx >> 5) & 63, khkw = idx >> 11;
  wT[idx] = (f16)w2[(oc * 32 + ic) * 9 + khkw];
}

__global__ void wt3_k(const float* __restrict__ w3, f16* __restrict__ wT)
{
  int idx = blockIdx.x * 256 + threadIdx.x;          // 73728
  int ic5 = idx & 31, oc = (idx >> 5) & 127, ch = idx >> 12;
  int khkw = ch >> 1, ich = ch & 1;
  int ic = ich * 32 + ic5;
  wT[idx] = (f16)w3[(oc * 64 + ic) * 9 + khkw];
}

// ---------------- conv2 MFMA: 32->64, stride 2, out 128x128, NHWC fp16 ----------------
// block = 4 waves; block covers (b, oh) x 64 oc x 128 ow; wave wv covers ow [wv*32, wv*32+32)
__global__ __launch_bounds__(256, 4) void conv2_m(const f16* __restrict__ in,
    const f16* __restrict__ wT, const float* __restrict__ b2, f16* __restrict__ out)
{
  const int oh = blockIdx.x, b = blockIdx.y;
  const int lane = threadIdx.x & 63, wv = threadIdx.x >> 6;
  const int n15 = lane & 15, quad = lane >> 4;
  const int ow0 = wv * 32;
  v4f acc[4][2] = {};
  const int ih0 = 2 * oh - 1;
  for (int kh = 0; kh < 3; kh++) {
    int ih = ih0 + kh;
    bool ihok = (unsigned)ih < 256u;
    const f16* inrow = in + ((long)(b * 256 + (ihok ? ih : 0))) * (256 * 32);
    for (int kw = 0; kw < 3; kw++) {
      int khkw = kh * 3 + kw;
      const f16* wp = wT + khkw * 2048 + n15 * 32 + quad * 8;
      v8h a0 = *(const v8h*)(wp);
      v8h a1 = *(const v8h*)(wp + 512);
      v8h a2 = *(const v8h*)(wp + 1024);
      v8h a3 = *(const v8h*)(wp + 1536);
      v8h bf[2];
      #pragma unroll
      for (int nt = 0; nt < 2; nt++) {
        int iw = 2 * (ow0 + nt * 16 + n15) + kw - 1;
        v8h v;
        #pragma unroll
        for (int k = 0; k < 8; k++) v[k] = (f16)0.f;
        if (ihok && (unsigned)iw < 256u) v = *(const v8h*)(inrow + iw * 32 + quad * 8);
        bf[nt] = v;
      }
      acc[0][0] = __builtin_amdgcn_mfma_f32_16x16x32_f16(a0, bf[0], acc[0][0], 0, 0, 0);
      acc[0][1] = __builtin_amdgcn_mfma_f32_16x16x32_f16(a0, bf[1], acc[0][1], 0, 0, 0);
      acc[1][0] = __builtin_amdgcn_mfma_f32_16x16x32_f16(a1, bf[0], acc[1][0], 0, 0, 0);
      acc[1][1] = __builtin_amdgcn_mfma_f32_16x16x32_f16(a1, bf[1], acc[1][1], 0, 0, 0);
      acc[2][0] = __builtin_amdgcn_mfma_f32_16x16x32_f16(a2, bf[0], acc[2][0], 0, 0, 0);
      acc[2][1] = __builtin_amdgcn_mfma_f32_16x16x32_f16(a2, bf[1], acc[2][1], 0, 0, 0);
      acc[3][0] = __builtin_amdgcn_mfma_f32_16x16x32_f16(a3, bf[0], acc[3][0], 0, 0, 0);
      acc[3][1] = __builtin_amdgcn_mfma_f32_16x16x32_f16(a3, bf[1], acc[3][1], 0, 0, 0);
    }
  }
  // epilogue: oc = mt*16 + quad*4 + r, ow = ow0 + nt*16 + n15
  #pragma unroll
  for (int mt = 0; mt < 4; mt++) {
    int oc0 = mt * 16 + quad * 4;
    float4 bb = *(const float4*)(b2 + oc0);
    #pragma unroll
    for (int nt = 0; nt < 2; nt++) {
      int ow = ow0 + nt * 16 + n15;
      h4 pk;
      #pragma unroll
      for (int r = 0; r < 4; r++) {
        float v = acc[mt][nt][r] + ((const float*)&bb)[r];
        pk[r] = (f16)(v > 0.f ? v : 0.f);
      }
      *(h4*)(out + (((long)(b * 128 + oh) * 128 + ow) * 64) + oc0) = pk;
    }
  }
}

// ---------------- conv3 MFMA: 64->128, stride 2, out 64x64 ----------------
// grid (64 oh, 32 b, 2 ocg); block covers 64 oc x 64 ow; wave wv covers ow [wv*16, wv*16+16)
// writes z fp32 NCHW (d_out) + fp16 NHWC (ws, for corr)
__global__ __launch_bounds__(256, 4) void conv3_m(const f16* __restrict__ in,
    const f16* __restrict__ wT, const float* __restrict__ b3,
    float* __restrict__ zout, f16* __restrict__ nhwc)
{
  const int oh = blockIdx.x, b = blockIdx.y, ocg = blockIdx.z;
  const int lane = threadIdx.x & 63, wv = threadIdx.x >> 6;
  const int n15 = lane & 15, quad = lane >> 4;
  const int ow = wv * 16 + n15;
  v4f acc[4] = {};
  const int ih0 = 2 * oh - 1;
  for (int kh = 0; kh < 3; kh++) {
    int ih = ih0 + kh;
    bool ihok = (unsigned)ih < 128u;
    const f16* inrow = in + ((long)(b * 128 + (ihok ? ih : 0))) * (128 * 64);
    for (int kw = 0; kw < 3; kw++) {
      int iw = 2 * ow + kw - 1;
      bool bok = ihok && (unsigned)iw < 128u;
      const f16* bp = inrow + iw * 64 + quad * 8;
      #pragma unroll
      for (int ich = 0; ich < 2; ich++) {
        int ch = (kh * 3 + kw) * 2 + ich;
        const f16* wp = wT + ((long)(ch * 128 + ocg * 64 + n15)) * 32 + quad * 8;
        v8h a0 = *(const v8h*)(wp);
        v8h a1 = *(const v8h*)(wp + 512);
        v8h a2 = *(const v8h*)(wp + 1024);
        v8h a3 = *(const v8h*)(wp + 1536);
        v8h bf;
        #pragma unroll
        for (int k = 0; k < 8; k++) bf[k] = (f16)0.f;
        if (bok) bf = *(const v8h*)(bp + ich * 32);
        acc[0] = __builtin_amdgcn_mfma_f32_16x16x32_f16(a0, bf, acc[0], 0, 0, 0);
        acc[1] = __builtin_amdgcn_mfma_f32_16x16x32_f16(a1, bf, acc[1], 0, 0, 0);
        acc[2] = __builtin_amdgcn_mfma_f32_16x16x32_f16(a2, bf, acc[2], 0, 0, 0);
        acc[3] = __builtin_amdgcn_mfma_f32_16x16x32_f16(a3, bf, acc[3], 0, 0, 0);
      }
    }
  }
  #pragma unroll
  for (int mt = 0; mt < 4; mt++) {
    int oc0 = ocg * 64 + mt * 16 + quad * 4;
    float4 bb = *(const float4*)(b3 + oc0);
    float rv[4];
    #pragma unroll
    for (int r = 0; r < 4; r++) {
      float v = acc[mt][r] + ((const float*)&bb)[r];
      rv[r] = v > 0.f ? v : 0.f;
    }
    // fp32 NCHW
    #pragma unroll
    for (int r = 0; r < 4; r++)
      zout[(((long)(b * 128 + oc0 + r) * 64 + oh) * 64) + ow] = rv[r];
    // fp16 NHWC
    h4 pk;
    #pragma unroll
    for (int r = 0; r < 4; r++) pk[r] = (f16)rv[r];
    *(h4*)(nhwc + (((long)(b * 64 + oh) * 64 + ow) * 128) + oc0) = pk;
  }
}

// ---------------- local correlation: K=13, C=128, from fp16 NHWC z ----------------
__global__ __launch_bounds__(256) void corr_k(const f16* __restrict__ zt, const f16* __restrict__ zt1,
    float* __restrict__ corr)
{
  const int h = blockIdx.x, b = blockIdx.y;
  __shared__ h8 sT[64][17];
  __shared__ h8 sU[64][17];
  const h8* tp = (const h8*)(zt + ((long)(b * 64 + h) * 64) * 128);
  for (int idx = threadIdx.x; idx < 1024; idx += 256)
    sT[idx >> 4][idx & 15] = tp[idx];
  const int w = threadIdx.x & 63, g = threadIdx.x >> 6;
  float* cb = corr + (long)b * 169 * 4096 + h * 64 + w;
  int wc[4]; bool ok[4];
  #pragma unroll
  for (int j = 0; j < 4; j++) {
    int kj = g * 4 + j;
    wc[j] = w + kj - 6;
    ok[j] = (kj < 13) && (wc[j] >= 0) && (wc[j] < 64);
  }
  for (int ki = 0; ki < 13; ki++) {
    int row = h + ki - 6;
    if (row < 0 || row > 63) {
      #pragma unroll
      for (int j = 0; j < 4; j++) {
        int kj = g * 4 + j;
        if (kj < 13) cb[(long)(ki * 13 + kj) * 4096] = 0.f;
      }
      continue;
    }
    __syncthreads();
    const h8* up = (const h8*)(zt1 + ((long)(b * 64 + row) * 64) * 128);
    for (int idx = threadIdx.x; idx < 1024; idx += 256)
      sU[idx >> 4][idx & 15] = up[idx];
    __syncthreads();
    float a[4] = {0.f, 0.f, 0.f, 0.f};
    for (int c8 = 0; c8 < 16; c8++) {
      h8 tv = sT[w][c8];
      #pragma unroll
      for (int j = 0; j < 4; j++) {
        if (!ok[j]) continue;
        h8 uv = sU[wc[j]][c8];
#if __has_builtin(__builtin_amdgcn_fdot2)
        a[j] = __builtin_amdgcn_fdot2(__builtin_shufflevector(tv, tv, 0, 1),
                                      __builtin_shufflevector(uv, uv, 0, 1), a[j], false);
        a[j] = __builtin_amdgcn_fdot2(__builtin_shufflevector(tv, tv, 2, 3),
                                      __builtin_shufflevector(uv, uv, 2, 3), a[j], false);
        a[j] = __builtin_amdgcn_fdot2(__builtin_shufflevector(tv, tv, 4, 5),
                                      __builtin_shufflevector(uv, uv, 4, 5), a[j], false);
        a[j] = __builtin_amdgcn_fdot2(__builtin_shufflevector(tv, tv, 6, 7),
                                      __builtin_shufflevector(uv, uv, 6, 7), a[j], false);
#else
        #pragma unroll
        for (int k = 0; k < 8; k++) a[j] += (float)tv[k] * (float)uv[k];
#endif
      }
    }
    #pragma unroll
    for (int j = 0; j < 4; j++) {
      int kj = g * 4 + j;
      if (kj < 13) cb[(long)(ki * 13 + kj) * 4096] = a[j] * INV_SQRT_C;
    }
  }
}

// ---------------- h_t: mean over 64x64 per (b, offset) ----------------
__global__ __launch_bounds__(256) void ht_k(const float* __restrict__ corr, float* __restrict__ ht)
{
  const float4* p = (const float4*)(corr + (long)blockIdx.x * 4096);
  float s = 0.f;
  for (int i = threadIdx.x; i < 1024; i += 256) {
    float4 v = p[i];
    s += v.x + v.y + v.z + v.w;
  }
  #pragma unroll
  for (int off = 32; off > 0; off >>= 1) s += __shfl_down(s, off, 64);
  __shared__ float ps[4];
  if ((threadIdx.x & 63) == 0) ps[threadIdx.x >> 6] = s;
  __syncthreads();
  if (threadIdx.x == 0) ht[blockIdx.x] = (ps[0] + ps[1] + ps[2] + ps[3]) * (1.f / 4096.f);
}

// ---------------- pred: h_t @ w_head.T + b_head ----------------
__global__ void pred_k(const float* __restrict__ ht, const float* __restrict__ wh,
                       const float* __restrict__ bh, float* __restrict__ pred)
{
  int t = threadIdx.x;
  int b = t >> 1, j = t & 1;
  float s = bh[j];
  for (int o = 0; o < 169; o++) s = fmaf(ht[b * 169 + o], wh[j * 169 + o], s);
  pred[b * 2 + j] = s;
}

extern "C" void kernel_launch(void* const* d_in, const int* in_sizes, int n_in,
                              void* d_out, int out_size, void* d_ws, size_t ws_size,
                              hipStream_t stream)
{
  (void)in_sizes; (void)n_in; (void)out_size; (void)ws_size;
  const float* img_t  = (const float*)d_in[0];
  const float* img_t1 = (const float*)d_in[1];
  const float* w1 = (const float*)d_in[2];
  const float* b1 = (const float*)d_in[3];
  const float* w2 = (const float*)d_in[4];
  const float* b2 = (const float*)d_in[5];
  const float* w3 = (const float*)d_in[6];
  const float* b3 = (const float*)d_in[7];
  const float* wh = (const float*)d_in[8];
  const float* bh = (const float*)d_in[9];
  float* out = (float*)d_out;

  // workspace layout (fp16 intermediates, 256 MiB total)
  char* ws = (char*)d_ws;
  f16* bufA = (f16*)ws;                       // conv1 out NHWC: 32*256*256*32*2 = 128 MiB
  f16* bufB = (f16*)(ws + 134217728L);        // conv2 out NHWC: 32*128*128*64*2 =  64 MiB
  f16* nhT  = (f16*)(ws + 201326592L);        // z_t  NHWC fp16: 32*64*64*128*2 =  32 MiB
  f16* nhT1 = (f16*)(ws + 234881024L);        // z_t1 NHWC fp16:                   32 MiB

  const long OUT_ZT   = 64;
  const long OUT_ZT1  = OUT_ZT + 16777216L;
  const long OUT_CORR = OUT_ZT1 + 16777216L;
  const long OUT_HT   = OUT_CORR + 22151168L;

  // transposed weights live in the (not-yet-written) corr region of d_out;
  // corr_k fully overwrites this region afterwards.
  f16* wT2 = (f16*)(out + OUT_CORR);          // 18432 f16 = 36 KiB
  f16* wT3 = wT2 + 18432;                     // 73728 f16 = 144 KiB

  wt2_k<<<72, 256, 0, stream>>>(w2, wT2);
  wt3_k<<<288, 256, 0, stream>>>(w3, wT3);

  for (int img = 0; img < 2; img++) {
    const float* src = img ? img_t1 : img_t;
    float* zdst = out + (img ? OUT_ZT1 : OUT_ZT);
    f16* nh = img ? nhT1 : nhT;
    conv1_k<<<dim3(256, 32), 256, 0, stream>>>(src, w1, b1, bufA);
    conv2_m<<<dim3(128, 32), 256, 0, stream>>>(bufA, wT2, b2, bufB);
    conv3_m<<<dim3(64, 32, 2), 256, 0, stream>>>(bufB, wT3, b3, zdst, nh);
  }
  corr_k<<<dim3(64, 32), 256, 0, stream>>>(nhT, nhT1, out + OUT_CORR);
  ht_k<<<5408, 256, 0, stream>>>(out + OUT_CORR, out + OUT_HT);
  pred_k<<<1, 64, 0, stream>>>(out + OUT_HT, wh, bh, out);
}